// Round 17
// baseline (182.019 us; speedup 1.0000x reference)
//
#include <hip/hip_runtime.h>
#include <hip/hip_fp16.h>

// 2-layer GCN, CSR-gather formulation (no float atomics).
// A_norm·(x@W1) = (A_norm·x)@W1 -> layer-1 aggregation in 12-ch space.
// CSR built by two-level LDS bucket sort (run-coalesced writes; scattered
// single-pass fill measured sector-bound at 64B/edge in r4/r7/r8).
// bbuf packed: (row<<7)|local_col (row < 2^17). rs payload = row only.
// RACE LESSON (r11): gather source values (dinv/x) must come from a PRIOR kernel.
// LAYOUT LESSON (r13): channel-slicing h2 trades traffic for 3x instructions.
// NT LESSON (r8/r15): nontemporal hints net-negative here (both directions).
// gather2: 2 nodes/wave, half2 channels -> per-edge issue count halved (r16).
// MLP LESSON (r17): fp16 LDS staging (ws/w1s/hs) halves LDS 74->38.5 KiB ->
// 4 blocks/CU (was 2, 16.6% occupancy, the r16 bottleneck at 54us).
// x and h2 in fp16 (measured safe r8-r16). MLP fused per 64-node tile.

#define IN_CH 12
#define HID 128
#define OUTC 64
#define PADH 132   // hidden-tile row stride in HALFS (264B: 4 bcast addrs, banks 8tr)
#define BSH 7      // bucket = 128 dest nodes
#define NBMAX 1024 // supports N <= 131072
#define CHUNK 4096 // edges per k_bucket block
#define SORTMAX 4096

// fused init: zero bcnt + convert x -> fp16
__global__ void k_init(int* __restrict__ bcnt, int nb,
                       const float* __restrict__ x, __half* __restrict__ x16, int n) {
    int i = blockIdx.x * blockDim.x + threadIdx.x;
    if (i < nb) bcnt[i] = 0;
    if (i < n) x16[i] = __float2half(x[i]);
}

// ---- CSR build pass 1: bucket histogram (LDS-privatized) ----
__global__ __launch_bounds__(256) void k_bhist(
    const int* __restrict__ col, int* __restrict__ bcnt, int E, int NB) {
    __shared__ int lh[NBMAX];
    int t = threadIdx.x;
    for (int i = t; i < NB; i += 256) lh[i] = 0;
    __syncthreads();
    int base = blockIdx.x * CHUNK;
    int end = min(base + CHUNK, E);
    for (int e = base + t; e < end; e += 256)
        atomicAdd(&lh[col[e] >> BSH], 1);
    __syncthreads();
    for (int i = t; i < NB; i += 256)
        if (lh[i]) atomicAdd(&bcnt[i], lh[i]);
}

// ---- pass 2: scan bucket counts -> bstart, gcur; also start[N]=E ----
__global__ __launch_bounds__(256) void k_bscan(
    const int* __restrict__ bcnt, int* __restrict__ bstart,
    int* __restrict__ gcur, int* __restrict__ startN, int E, int NB) {
    __shared__ int part[256];
    int t = threadIdx.x;
    int v[4]; int s = 0;
#pragma unroll
    for (int j = 0; j < 4; ++j) { int b = t * 4 + j; v[j] = (b < NB) ? bcnt[b] : 0; s += v[j]; }
    part[t] = s;
    __syncthreads();
    for (int off = 1; off < 256; off <<= 1) {
        int u = (t >= off) ? part[t - off] : 0;
        __syncthreads();
        part[t] += u;
        __syncthreads();
    }
    int base = (t > 0) ? part[t - 1] : 0;
#pragma unroll
    for (int j = 0; j < 4; ++j) {
        int b = t * 4 + j;
        if (b < NB) { bstart[b] = base; gcur[b] = base; }
        base += v[j];
    }
    if (t == 255) bstart[NB] = base;  // == E
    if (t == 0) *startN = E;          // start[N] = E
}

// ---- pass 3: LDS-staged bucket append; writes packed (row<<7)|lcol ----
__global__ __launch_bounds__(256) void k_bucket(
    const int* __restrict__ row, const int* __restrict__ col,
    int* __restrict__ gcur, int* __restrict__ bbuf, int E, int NB) {
    __shared__ int lh[NBMAX], lstart[NBMAX], lcur[NBMAX], gb[NBMAX];
    __shared__ int part[256];
    __shared__ int2 lbuf[CHUNK];  // 32 KiB
    int t = threadIdx.x;
    for (int i = t; i < NB; i += 256) lh[i] = 0;
    __syncthreads();
    int base0 = blockIdx.x * CHUNK;
    int end = min(base0 + CHUNK, E);
    for (int e = base0 + t; e < end; e += 256)
        atomicAdd(&lh[col[e] >> BSH], 1);
    __syncthreads();
    int v[4]; int s = 0;
#pragma unroll
    for (int j = 0; j < 4; ++j) { int b = t * 4 + j; v[j] = (b < NB) ? lh[b] : 0; s += v[j]; }
    part[t] = s;
    __syncthreads();
    for (int off = 1; off < 256; off <<= 1) {
        int u = (t >= off) ? part[t - off] : 0;
        __syncthreads();
        part[t] += u;
        __syncthreads();
    }
    int pb = (t > 0) ? part[t - 1] : 0;
#pragma unroll
    for (int j = 0; j < 4; ++j) {
        int b = t * 4 + j;
        if (b < NB) lstart[b] = pb;
        pb += v[j];
    }
    __syncthreads();
    for (int i = t; i < NB; i += 256) {
        int c = lh[i];
        gb[i] = c ? atomicAdd(&gcur[i], c) : 0;
        lcur[i] = lstart[i];
    }
    __syncthreads();
    for (int e = base0 + t; e < end; e += 256) {
        int c = col[e];
        int p = atomicAdd(&lcur[c >> BSH], 1);
        lbuf[p] = make_int2(row[e], c);
    }
    __syncthreads();
    int cN = end - base0;
    for (int i = t; i < cN; i += 256) {
        int2 rc = lbuf[i];
        int b = rc.y >> BSH;
        bbuf[gb[b] + (i - lstart[b])] = (rc.x << BSH) | (rc.y & 127);
    }
}

// ---- pass 4: per-bucket CSR: start/dinv + LDS sort -> coalesced rs write ----
__global__ __launch_bounds__(256) void k_csr(
    const int* __restrict__ bstart, const int* __restrict__ bbuf,
    int* __restrict__ start, float* __restrict__ dinv,
    int* __restrict__ rs, int N) {
    int me = blockIdx.x;
    int lo = me << BSH;
    int bs = bstart[me], be = bstart[me + 1];
    int cntb = be - bs;
    __shared__ int lh[128], lsc[128];
    __shared__ int lsort[SORTMAX];  // 16 KiB
    int t = threadIdx.x;
    bool lds_ok = (cntb <= SORTMAX);
    if (t < 128) lh[t] = 0;
    __syncthreads();
    for (int i = t; i < cntb; i += 256)
        atomicAdd(&lh[bbuf[bs + i] & 127], 1);
    __syncthreads();
    if (t < 128) lsc[t] = lh[t];
    __syncthreads();
    for (int off = 1; off < 128; off <<= 1) {
        int u = (t < 128 && t >= off) ? lsc[t - off] : 0;
        __syncthreads();
        if (t < 128) lsc[t] += u;
        __syncthreads();
    }
    if (t < 128) {
        int excl = lsc[t] - lh[t];
        int n = lo + t;
        if (n < N) {
            start[n] = bs + excl;
            dinv[n] = rsqrtf((float)lh[t] + 1.0f);
        }
        lsc[t] = excl;  // reuse as cursor
    }
    __syncthreads();
    for (int i = t; i < cntb; i += 256) {
        int v = bbuf[bs + i];
        int p = atomicAdd(&lsc[v & 127], 1);
        int r = v >> BSH;
        if (lds_ok) lsort[p] = r; else rs[bs + p] = r;
    }
    __syncthreads();
    if (lds_ok)  // coalesced rs write-out
        for (int i = t; i < cntb; i += 256) rs[bs + i] = lsort[i];
}

// ---- layer 1 gather: aggx = A_norm·x (12 ch, fp16 x, 8-deep pipeline) ----
__global__ __launch_bounds__(192) void k_gather_x(
    const int* __restrict__ start, const float* __restrict__ dinv,
    const int* __restrict__ rs, const __half* __restrict__ x16,
    float* __restrict__ aggx, int N) {
    int ln = threadIdx.x / 12;
    int c  = threadIdx.x % 12;
    int n  = blockIdx.x * 16 + ln;
    if (n >= N) return;
    float dv = dinv[n];
    int s0 = start[n], k = start[n + 1] - s0;
    float acc = __half2float(x16[(size_t)n * IN_CH + c]) * dv * dv;
    int j = 0;
    for (; j + 8 <= k; j += 8) {
        int r[8];
#pragma unroll
        for (int q = 0; q < 8; ++q) r[q] = rs[s0 + j + q];
        float nm[8], vv[8];
#pragma unroll
        for (int q = 0; q < 8; ++q) nm[q] = dinv[r[q]] * dv;
#pragma unroll
        for (int q = 0; q < 8; ++q) vv[q] = __half2float(x16[(size_t)r[q] * IN_CH + c]);
#pragma unroll
        for (int q = 0; q < 8; ++q) acc = fmaf(vv[q], nm[q], acc);
    }
    for (; j + 4 <= k; j += 4) {
        int r0 = rs[s0 + j], r1 = rs[s0 + j + 1], r2 = rs[s0 + j + 2], r3 = rs[s0 + j + 3];
        float n0 = dinv[r0] * dv, n1 = dinv[r1] * dv, n2 = dinv[r2] * dv, n3 = dinv[r3] * dv;
        float v0 = __half2float(x16[(size_t)r0 * IN_CH + c]);
        float v1 = __half2float(x16[(size_t)r1 * IN_CH + c]);
        float v2 = __half2float(x16[(size_t)r2 * IN_CH + c]);
        float v3 = __half2float(x16[(size_t)r3 * IN_CH + c]);
        acc = fmaf(v0, n0, acc); acc = fmaf(v1, n1, acc);
        acc = fmaf(v2, n2, acc); acc = fmaf(v3, n3, acc);
    }
    for (; j < k; ++j) {
        int r = rs[s0 + j];
        acc = fmaf(__half2float(x16[(size_t)r * IN_CH + c]), dinv[r] * dv, acc);
    }
    aggx[(size_t)n * IN_CH + c] = acc;
}

// ---- fused MLP: h2 = fp16( relu(aggx@W1 + b1) @ W2 ), per 64-node tile ----
// fp16 LDS staging: ws/w1s/hs in half -> 38.5 KiB total -> 4 blocks/CU.
__global__ __launch_bounds__(256) void k_mlp(
    const float* __restrict__ aggx, const float* __restrict__ W1,
    const float* __restrict__ b1, const float* __restrict__ W2,
    __half* __restrict__ h2, int N) {
    __shared__ __half wsh[HID * OUTC];   // 16 KiB  W2 fp16
    __shared__ __half w1h[IN_CH * HID];  // 3 KiB   W1 fp16
    __shared__ float  axs[64 * IN_CH];   // 3 KiB
    __shared__ __half hsh[64 * PADH];    // 16.5 KiB hidden fp16
    int t = threadIdx.x;
    // stage W2 -> fp16 (2048 float4 -> 4096 half2)
    for (int i = t; i < (HID * OUTC) / 4; i += 256) {
        float4 v = ((const float4*)W2)[i];
        ((__half2*)wsh)[2 * i]     = __floats2half2_rn(v.x, v.y);
        ((__half2*)wsh)[2 * i + 1] = __floats2half2_rn(v.z, v.w);
    }
    // stage W1 -> fp16 (384 float4)
    for (int i = t; i < (IN_CH * HID) / 4; i += 256) {
        float4 v = ((const float4*)W1)[i];
        ((__half2*)w1h)[2 * i]     = __floats2half2_rn(v.x, v.y);
        ((__half2*)w1h)[2 * i + 1] = __floats2half2_rn(v.z, v.w);
    }
    long long base = (long long)blockIdx.x * 64;
    for (int i = t; i < 64 * IN_CH; i += 256) {
        long long n = base + i / IN_CH;
        axs[i] = (n < N) ? aggx[base * IN_CH + i] : 0.0f;
    }
    __syncthreads();
    // hidden: hsh[row][k] = fp16(relu(sum_j axs[row][j]*W1[j][k] + b1[k]))
    {
        int k    = t & 127;
        int half = t >> 7;
        float w[IN_CH];
#pragma unroll
        for (int j = 0; j < IN_CH; ++j) w[j] = __half2float(w1h[j * HID + k]);
        float bb = b1[k];
        for (int r = 0; r < 32; ++r) {
            int row = half * 32 + r;
            float acc = bb;
#pragma unroll
            for (int j = 0; j < IN_CH; ++j)
                acc = fmaf(axs[row * IN_CH + j], w[j], acc);
            hsh[row * PADH + k] = __float2half(fmaxf(acc, 0.0f));
        }
    }
    __syncthreads();
    // output: 64x64 tile, 4x4 register tile per thread, fp16 LDS operands
    int tc = t & 15;
    int tr = t >> 4;
    float acc[4][4] = {};
#pragma unroll 4
    for (int k = 0; k < HID; k += 4) {
        float aF[4][4], wF[4][4];
#pragma unroll
        for (int j = 0; j < 4; ++j) {
            const __half2* ph = (const __half2*)(hsh + (4 * tr + j) * PADH + k);
            float2 lo = __half22float2(ph[0]);
            float2 hi = __half22float2(ph[1]);
            aF[j][0] = lo.x; aF[j][1] = lo.y; aF[j][2] = hi.x; aF[j][3] = hi.y;
        }
#pragma unroll
        for (int kk = 0; kk < 4; ++kk) {
            const __half2* pw = (const __half2*)(wsh + (k + kk) * OUTC + 4 * tc);
            float2 lo = __half22float2(pw[0]);
            float2 hi = __half22float2(pw[1]);
            wF[kk][0] = lo.x; wF[kk][1] = lo.y; wF[kk][2] = hi.x; wF[kk][3] = hi.y;
        }
#pragma unroll
        for (int kk = 0; kk < 4; ++kk)
#pragma unroll
            for (int j = 0; j < 4; ++j) {
                acc[j][0] = fmaf(aF[j][kk], wF[kk][0], acc[j][0]);
                acc[j][1] = fmaf(aF[j][kk], wF[kk][1], acc[j][1]);
                acc[j][2] = fmaf(aF[j][kk], wF[kk][2], acc[j][2]);
                acc[j][3] = fmaf(aF[j][kk], wF[kk][3], acc[j][3]);
            }
    }
#pragma unroll
    for (int j = 0; j < 4; ++j) {
        long long r = base + 4 * tr + j;
        if (r < N) {
            __half2* d = (__half2*)(h2 + r * OUTC + 4 * tc);
            d[0] = __floats2half2_rn(acc[j][0], acc[j][1]);
            d[1] = __floats2half2_rn(acc[j][2], acc[j][3]);
        }
    }
}

// ---- layer 2 gather: out = A_norm·h2 + b2 ----
// 2 nodes per wave (half-wave each), 2 channels per lane via half2:
// per-edge wave-issue count halved vs 1-node/wave; h2 reads stay coalesced.
__global__ __launch_bounds__(256) void k_gather2(
    const int* __restrict__ start, const float* __restrict__ dinv,
    const int* __restrict__ rs, const __half* __restrict__ h2,
    const float* __restrict__ b2, float* __restrict__ out, int N) {
    int n = blockIdx.x * 8 + (threadIdx.x >> 5);  // 8 nodes per 256-thr block
    if (n >= N) return;
    int l = threadIdx.x & 31;                     // channels 2l, 2l+1
    const __half2* hv = (const __half2*)h2;       // 32 half2 per row
    float dv = dinv[n];
    int s0 = start[n], k = start[n + 1] - s0;
    float2 bb = *(const float2*)(b2 + 2 * l);
    float2 hn = __half22float2(hv[(size_t)n * 32 + l]);
    float dvv = dv * dv;
    float ax = fmaf(hn.x, dvv, bb.x);
    float ay = fmaf(hn.y, dvv, bb.y);
    int j = 0;
    for (; j + 8 <= k; j += 8) {
        int r[8];
#pragma unroll
        for (int q = 0; q < 8; ++q) r[q] = rs[s0 + j + q];
        float nm[8];
#pragma unroll
        for (int q = 0; q < 8; ++q) nm[q] = dinv[r[q]] * dv;
        float2 vv[8];
#pragma unroll
        for (int q = 0; q < 8; ++q) vv[q] = __half22float2(hv[(size_t)r[q] * 32 + l]);
#pragma unroll
        for (int q = 0; q < 8; ++q) {
            ax = fmaf(vv[q].x, nm[q], ax);
            ay = fmaf(vv[q].y, nm[q], ay);
        }
    }
    for (; j + 4 <= k; j += 4) {
        int r0 = rs[s0 + j], r1 = rs[s0 + j + 1], r2 = rs[s0 + j + 2], r3 = rs[s0 + j + 3];
        float n0 = dinv[r0] * dv, n1 = dinv[r1] * dv, n2 = dinv[r2] * dv, n3 = dinv[r3] * dv;
        float2 v0 = __half22float2(hv[(size_t)r0 * 32 + l]);
        float2 v1 = __half22float2(hv[(size_t)r1 * 32 + l]);
        float2 v2 = __half22float2(hv[(size_t)r2 * 32 + l]);
        float2 v3 = __half22float2(hv[(size_t)r3 * 32 + l]);
        ax = fmaf(v0.x, n0, ax); ay = fmaf(v0.y, n0, ay);
        ax = fmaf(v1.x, n1, ax); ay = fmaf(v1.y, n1, ay);
        ax = fmaf(v2.x, n2, ax); ay = fmaf(v2.y, n2, ay);
        ax = fmaf(v3.x, n3, ax); ay = fmaf(v3.y, n3, ay);
    }
    for (; j < k; ++j) {
        int r = rs[s0 + j];
        float nm = dinv[r] * dv;
        float2 vv = __half22float2(hv[(size_t)r * 32 + l]);
        ax = fmaf(vv.x, nm, ax);
        ay = fmaf(vv.y, nm, ay);
    }
    *(float2*)(out + (size_t)n * OUTC + 2 * l) = make_float2(ax, ay);
}

extern "C" void kernel_launch(void* const* d_in, const int* in_sizes, int n_in,
                              void* d_out, int out_size, void* d_ws, size_t ws_size,
                              hipStream_t stream) {
    const float* x  = (const float*)d_in[0];
    const int*   ei = (const int*)d_in[1];
    const float* W1 = (const float*)d_in[2];
    const float* b1 = (const float*)d_in[3];
    const float* W2 = (const float*)d_in[4];
    const float* b2 = (const float*)d_in[5];
    float* out = (float*)d_out;

    const int N = in_sizes[0] / IN_CH;
    const int E = in_sizes[1] / 2;
    const int* row = ei;
    const int* col = ei + E;
    const int NB = (N + 127) >> BSH;  // 782 for N=100000 (<= NBMAX)

    char* ws = (char*)d_ws;
    int*    bcnt   = (int*)ws;                      // NB (zeroed by k_init)
    int*    bstart = bcnt + NBMAX;                  // NB+1
    int*    gcur   = bstart + NBMAX + 8;            // NB
    int*    start  = gcur + NBMAX;                  // N+1
    float*  dinv   = (float*)(start + N + 8);       // N
    char*   p      = (char*)(dinv + N);
    p = (char*)(((uintptr_t)p + 255) & ~(uintptr_t)255);
    int*    bbuf   = (int*)p;                       // E packed ints (6.4 MB)
    int*    rs     = bbuf + E;                      // E ints (6.4 MB)
    __half* x16    = (__half*)(rs + E);             // N*12 fp16
    float*  aggx   = (float*)(x16 + (size_t)N * IN_CH + 8);   // N*12 f32
    __half* h2     = (__half*)(aggx + (size_t)N * IN_CH);     // N*64 fp16

    const int nchunks = (E + CHUNK - 1) / CHUNK;

    k_init<<<(N * IN_CH + 255) / 256, 256, 0, stream>>>(bcnt, NB, x, x16, N * IN_CH);
    k_bhist<<<nchunks, 256, 0, stream>>>(col, bcnt, E, NB);
    k_bscan<<<1, 256, 0, stream>>>(bcnt, bstart, gcur, start + N, E, NB);
    k_bucket<<<nchunks, 256, 0, stream>>>(row, col, gcur, bbuf, E, NB);
    k_csr<<<NB, 256, 0, stream>>>(bstart, bbuf, start, dinv, rs, N);

    k_gather_x<<<(N + 15) / 16, 192, 0, stream>>>(start, dinv, rs, x16, aggx, N);
    k_mlp<<<(N + 63) / 64, 256, 0, stream>>>(aggx, W1, b1, W2, h2, N);
    k_gather2<<<(N + 7) / 8, 256, 0, stream>>>(start, dinv, rs, h2, b2, out, N);
}

// Round 18
// 153.658 us; speedup vs baseline: 1.1846x; 1.1846x over previous
//
#include <hip/hip_runtime.h>
#include <hip/hip_fp16.h>

// 2-layer GCN, CSR-gather formulation (no float atomics).
// A_norm·(x@W1) = (A_norm·x)@W1 -> layer-1 aggregation in 12-ch space.
// CSR built by two-level LDS bucket sort (run-coalesced writes; scattered
// single-pass fill measured sector-bound at 64B/edge in r4/r7/r8).
// bbuf packed: (row<<7)|local_col (row < 2^17). rs payload = row only.
// RACE LESSON (r11): gather source values (dinv/x) must come from a PRIOR kernel.
// LAYOUT LESSON (r13): channel-slicing h2 trades traffic for 3x instructions.
// NT LESSON (r8/r15): nontemporal hints net-negative here (both directions).
// gather2: 2 nodes/wave, half2 channels -> per-edge issue count halved (r16).
// MLP LESSON (r17): k_mlp was LDS-pipe-bound (~640 LDS ops/wave = 58us).
// r18: MFMA mlp — hidden computed straight into A-fragments (regs), W2
// staged transposed for b128 B-frags; ~76 LDS ops/wave, matrix pipe does GEMM.
// x and h2 in fp16 (measured safe r8-r17). MLP fused per 64-node tile.

#define IN_CH 12
#define HID 128
#define OUTC 64
#define BSH 7      // bucket = 128 dest nodes
#define NBMAX 1024 // supports N <= 131072
#define CHUNK 4096 // edges per k_bucket block
#define SORTMAX 4096
#define W2TS 136   // w2t row stride in halfs (272B: 16B-aligned b128, 2-way banks)

typedef _Float16 f16x8 __attribute__((ext_vector_type(8)));
typedef float f32x4 __attribute__((ext_vector_type(4)));

// fused init: zero bcnt + convert x -> fp16
__global__ void k_init(int* __restrict__ bcnt, int nb,
                       const float* __restrict__ x, __half* __restrict__ x16, int n) {
    int i = blockIdx.x * blockDim.x + threadIdx.x;
    if (i < nb) bcnt[i] = 0;
    if (i < n) x16[i] = __float2half(x[i]);
}

// ---- CSR build pass 1: bucket histogram (LDS-privatized) ----
__global__ __launch_bounds__(256) void k_bhist(
    const int* __restrict__ col, int* __restrict__ bcnt, int E, int NB) {
    __shared__ int lh[NBMAX];
    int t = threadIdx.x;
    for (int i = t; i < NB; i += 256) lh[i] = 0;
    __syncthreads();
    int base = blockIdx.x * CHUNK;
    int end = min(base + CHUNK, E);
    for (int e = base + t; e < end; e += 256)
        atomicAdd(&lh[col[e] >> BSH], 1);
    __syncthreads();
    for (int i = t; i < NB; i += 256)
        if (lh[i]) atomicAdd(&bcnt[i], lh[i]);
}

// ---- pass 2: scan bucket counts -> bstart, gcur; also start[N]=E ----
__global__ __launch_bounds__(256) void k_bscan(
    const int* __restrict__ bcnt, int* __restrict__ bstart,
    int* __restrict__ gcur, int* __restrict__ startN, int E, int NB) {
    __shared__ int part[256];
    int t = threadIdx.x;
    int v[4]; int s = 0;
#pragma unroll
    for (int j = 0; j < 4; ++j) { int b = t * 4 + j; v[j] = (b < NB) ? bcnt[b] : 0; s += v[j]; }
    part[t] = s;
    __syncthreads();
    for (int off = 1; off < 256; off <<= 1) {
        int u = (t >= off) ? part[t - off] : 0;
        __syncthreads();
        part[t] += u;
        __syncthreads();
    }
    int base = (t > 0) ? part[t - 1] : 0;
#pragma unroll
    for (int j = 0; j < 4; ++j) {
        int b = t * 4 + j;
        if (b < NB) { bstart[b] = base; gcur[b] = base; }
        base += v[j];
    }
    if (t == 255) bstart[NB] = base;  // == E
    if (t == 0) *startN = E;          // start[N] = E
}

// ---- pass 3: LDS-staged bucket append; writes packed (row<<7)|lcol ----
__global__ __launch_bounds__(256) void k_bucket(
    const int* __restrict__ row, const int* __restrict__ col,
    int* __restrict__ gcur, int* __restrict__ bbuf, int E, int NB) {
    __shared__ int lh[NBMAX], lstart[NBMAX], lcur[NBMAX], gb[NBMAX];
    __shared__ int part[256];
    __shared__ int2 lbuf[CHUNK];  // 32 KiB
    int t = threadIdx.x;
    for (int i = t; i < NB; i += 256) lh[i] = 0;
    __syncthreads();
    int base0 = blockIdx.x * CHUNK;
    int end = min(base0 + CHUNK, E);
    for (int e = base0 + t; e < end; e += 256)
        atomicAdd(&lh[col[e] >> BSH], 1);
    __syncthreads();
    int v[4]; int s = 0;
#pragma unroll
    for (int j = 0; j < 4; ++j) { int b = t * 4 + j; v[j] = (b < NB) ? lh[b] : 0; s += v[j]; }
    part[t] = s;
    __syncthreads();
    for (int off = 1; off < 256; off <<= 1) {
        int u = (t >= off) ? part[t - off] : 0;
        __syncthreads();
        part[t] += u;
        __syncthreads();
    }
    int pb = (t > 0) ? part[t - 1] : 0;
#pragma unroll
    for (int j = 0; j < 4; ++j) {
        int b = t * 4 + j;
        if (b < NB) lstart[b] = pb;
        pb += v[j];
    }
    __syncthreads();
    for (int i = t; i < NB; i += 256) {
        int c = lh[i];
        gb[i] = c ? atomicAdd(&gcur[i], c) : 0;
        lcur[i] = lstart[i];
    }
    __syncthreads();
    for (int e = base0 + t; e < end; e += 256) {
        int c = col[e];
        int p = atomicAdd(&lcur[c >> BSH], 1);
        lbuf[p] = make_int2(row[e], c);
    }
    __syncthreads();
    int cN = end - base0;
    for (int i = t; i < cN; i += 256) {
        int2 rc = lbuf[i];
        int b = rc.y >> BSH;
        bbuf[gb[b] + (i - lstart[b])] = (rc.x << BSH) | (rc.y & 127);
    }
}

// ---- pass 4: per-bucket CSR: start/dinv + LDS sort -> coalesced rs write ----
__global__ __launch_bounds__(256) void k_csr(
    const int* __restrict__ bstart, const int* __restrict__ bbuf,
    int* __restrict__ start, float* __restrict__ dinv,
    int* __restrict__ rs, int N) {
    int me = blockIdx.x;
    int lo = me << BSH;
    int bs = bstart[me], be = bstart[me + 1];
    int cntb = be - bs;
    __shared__ int lh[128], lsc[128];
    __shared__ int lsort[SORTMAX];  // 16 KiB
    int t = threadIdx.x;
    bool lds_ok = (cntb <= SORTMAX);
    if (t < 128) lh[t] = 0;
    __syncthreads();
    for (int i = t; i < cntb; i += 256)
        atomicAdd(&lh[bbuf[bs + i] & 127], 1);
    __syncthreads();
    if (t < 128) lsc[t] = lh[t];
    __syncthreads();
    for (int off = 1; off < 128; off <<= 1) {
        int u = (t < 128 && t >= off) ? lsc[t - off] : 0;
        __syncthreads();
        if (t < 128) lsc[t] += u;
        __syncthreads();
    }
    if (t < 128) {
        int excl = lsc[t] - lh[t];
        int n = lo + t;
        if (n < N) {
            start[n] = bs + excl;
            dinv[n] = rsqrtf((float)lh[t] + 1.0f);
        }
        lsc[t] = excl;  // reuse as cursor
    }
    __syncthreads();
    for (int i = t; i < cntb; i += 256) {
        int v = bbuf[bs + i];
        int p = atomicAdd(&lsc[v & 127], 1);
        int r = v >> BSH;
        if (lds_ok) lsort[p] = r; else rs[bs + p] = r;
    }
    __syncthreads();
    if (lds_ok)  // coalesced rs write-out
        for (int i = t; i < cntb; i += 256) rs[bs + i] = lsort[i];
}

// ---- layer 1 gather: aggx = A_norm·x (12 ch, fp16 x, 8-deep pipeline) ----
__global__ __launch_bounds__(192) void k_gather_x(
    const int* __restrict__ start, const float* __restrict__ dinv,
    const int* __restrict__ rs, const __half* __restrict__ x16,
    float* __restrict__ aggx, int N) {
    int ln = threadIdx.x / 12;
    int c  = threadIdx.x % 12;
    int n  = blockIdx.x * 16 + ln;
    if (n >= N) return;
    float dv = dinv[n];
    int s0 = start[n], k = start[n + 1] - s0;
    float acc = __half2float(x16[(size_t)n * IN_CH + c]) * dv * dv;
    int j = 0;
    for (; j + 8 <= k; j += 8) {
        int r[8];
#pragma unroll
        for (int q = 0; q < 8; ++q) r[q] = rs[s0 + j + q];
        float nm[8], vv[8];
#pragma unroll
        for (int q = 0; q < 8; ++q) nm[q] = dinv[r[q]] * dv;
#pragma unroll
        for (int q = 0; q < 8; ++q) vv[q] = __half2float(x16[(size_t)r[q] * IN_CH + c]);
#pragma unroll
        for (int q = 0; q < 8; ++q) acc = fmaf(vv[q], nm[q], acc);
    }
    for (; j + 4 <= k; j += 4) {
        int r0 = rs[s0 + j], r1 = rs[s0 + j + 1], r2 = rs[s0 + j + 2], r3 = rs[s0 + j + 3];
        float n0 = dinv[r0] * dv, n1 = dinv[r1] * dv, n2 = dinv[r2] * dv, n3 = dinv[r3] * dv;
        float v0 = __half2float(x16[(size_t)r0 * IN_CH + c]);
        float v1 = __half2float(x16[(size_t)r1 * IN_CH + c]);
        float v2 = __half2float(x16[(size_t)r2 * IN_CH + c]);
        float v3 = __half2float(x16[(size_t)r3 * IN_CH + c]);
        acc = fmaf(v0, n0, acc); acc = fmaf(v1, n1, acc);
        acc = fmaf(v2, n2, acc); acc = fmaf(v3, n3, acc);
    }
    for (; j < k; ++j) {
        int r = rs[s0 + j];
        acc = fmaf(__half2float(x16[(size_t)r * IN_CH + c]), dinv[r] * dv, acc);
    }
    aggx[(size_t)n * IN_CH + c] = acc;
}

// ---- fused MLP via MFMA: h2 = fp16( relu(aggx@W1 + b1) @ W2 ) ----
// Block = 64 nodes, 4 waves; wave = 16-node x 64-ch tile.
// Hidden computed per-lane straight into A-fragments (no LDS round-trip):
// lane holds hidden[row=lane&15][k = f*32 + (lane>>4)*8 + 0..7].
// B-frag: w2t[col][k] transposed LDS, 1 ds_read_b128 per (col-tile, f).
// D layout (m89-verified): col=lane&15, row=(lane>>4)*4+reg.
__global__ __launch_bounds__(256) void k_mlp(
    const float* __restrict__ aggx, const float* __restrict__ W1,
    const float* __restrict__ b1, const float* __restrict__ W2,
    __half* __restrict__ h2, int N) {
    __shared__ _Float16 w2t[OUTC * W2TS];   // W2^T [c][k], 17 KiB
    __shared__ _Float16 w1h[IN_CH * HID];   // W1 [j][k], 3 KiB
    int t = threadIdx.x;
    for (int i = t; i < HID * OUTC; i += 256) {
        int k = i >> 6, c = i & 63;
        w2t[c * W2TS + k] = (_Float16)W2[i];
    }
    for (int i = t; i < IN_CH * HID; i += 256)
        w1h[i] = (_Float16)W1[i];
    __syncthreads();

    int lane = t & 63;
    int wv   = t >> 6;               // wave 0..3
    int mrow = lane & 15;            // A-row / B-col / D-col within tile
    int kg   = lane >> 4;            // k-group 0..3
    long long base = (long long)blockIdx.x * 64 + wv * 16;
    long long nrow = base + mrow;
    long long ncl  = (nrow < N) ? nrow : (long long)(N - 1);

    // aggx row -> 12 regs (lanes 16-63 redundant with 0-15: same cachelines)
    float ax[12];
    {
        const float4* ap = (const float4*)(aggx + ncl * IN_CH);
        float4 a0 = ap[0], a1 = ap[1], a2 = ap[2];
        ax[0] = a0.x; ax[1] = a0.y; ax[2]  = a0.z; ax[3]  = a0.w;
        ax[4] = a1.x; ax[5] = a1.y; ax[6]  = a1.z; ax[7]  = a1.w;
        ax[8] = a2.x; ax[9] = a2.y; ax[10] = a2.z; ax[11] = a2.w;
    }

    f32x4 acc[4] = {{0.f,0.f,0.f,0.f}, {0.f,0.f,0.f,0.f},
                    {0.f,0.f,0.f,0.f}, {0.f,0.f,0.f,0.f}};
#pragma unroll
    for (int f = 0; f < 4; ++f) {
        int kk = f * 32 + kg * 8;
        // hidden[nrow][kk..kk+7] in f32
        float hv[8];
        float4 bb0 = *(const float4*)(b1 + kk);
        float4 bb1 = *(const float4*)(b1 + kk + 4);
        hv[0] = bb0.x; hv[1] = bb0.y; hv[2] = bb0.z; hv[3] = bb0.w;
        hv[4] = bb1.x; hv[5] = bb1.y; hv[6] = bb1.z; hv[7] = bb1.w;
#pragma unroll
        for (int j = 0; j < IN_CH; ++j) {
            const __half2* wp = (const __half2*)(w1h + j * HID + kk);  // broadcast
            float2 w0 = __half22float2(wp[0]);
            float2 w1v = __half22float2(wp[1]);
            float2 w2v = __half22float2(wp[2]);
            float2 w3 = __half22float2(wp[3]);
            float a = ax[j];
            hv[0] = fmaf(a, w0.x, hv[0]);  hv[1] = fmaf(a, w0.y, hv[1]);
            hv[2] = fmaf(a, w1v.x, hv[2]); hv[3] = fmaf(a, w1v.y, hv[3]);
            hv[4] = fmaf(a, w2v.x, hv[4]); hv[5] = fmaf(a, w2v.y, hv[5]);
            hv[6] = fmaf(a, w3.x, hv[6]);  hv[7] = fmaf(a, w3.y, hv[7]);
        }
        f16x8 af;
#pragma unroll
        for (int i = 0; i < 8; ++i) af[i] = (_Float16)fmaxf(hv[i], 0.0f);
#pragma unroll
        for (int c = 0; c < 4; ++c) {
            f16x8 bf = *(const f16x8*)(w2t + (c * 16 + mrow) * W2TS + kk);
            acc[c] = __builtin_amdgcn_mfma_f32_16x16x32_f16(af, bf, acc[c], 0, 0, 0);
        }
    }
    // D write: lane holds D[kg*4+r][mrow] of each col-tile c
#pragma unroll
    for (int r = 0; r < 4; ++r) {
        long long node = base + kg * 4 + r;
        if (node < N) {
            __half* dp = h2 + node * OUTC + mrow;
#pragma unroll
            for (int c = 0; c < 4; ++c)
                dp[c * 16] = __float2half(acc[c][r]);
        }
    }
}

// ---- layer 2 gather: out = A_norm·h2 + b2 ----
// 2 nodes per wave (half-wave each), 2 channels per lane via half2.
__global__ __launch_bounds__(256) void k_gather2(
    const int* __restrict__ start, const float* __restrict__ dinv,
    const int* __restrict__ rs, const __half* __restrict__ h2,
    const float* __restrict__ b2, float* __restrict__ out, int N) {
    int n = blockIdx.x * 8 + (threadIdx.x >> 5);  // 8 nodes per 256-thr block
    if (n >= N) return;
    int l = threadIdx.x & 31;                     // channels 2l, 2l+1
    const __half2* hv = (const __half2*)h2;       // 32 half2 per row
    float dv = dinv[n];
    int s0 = start[n], k = start[n + 1] - s0;
    float2 bb = *(const float2*)(b2 + 2 * l);
    float2 hn = __half22float2(hv[(size_t)n * 32 + l]);
    float dvv = dv * dv;
    float ax = fmaf(hn.x, dvv, bb.x);
    float ay = fmaf(hn.y, dvv, bb.y);
    int j = 0;
    for (; j + 8 <= k; j += 8) {
        int r[8];
#pragma unroll
        for (int q = 0; q < 8; ++q) r[q] = rs[s0 + j + q];
        float nm[8];
#pragma unroll
        for (int q = 0; q < 8; ++q) nm[q] = dinv[r[q]] * dv;
        float2 vv[8];
#pragma unroll
        for (int q = 0; q < 8; ++q) vv[q] = __half22float2(hv[(size_t)r[q] * 32 + l]);
#pragma unroll
        for (int q = 0; q < 8; ++q) {
            ax = fmaf(vv[q].x, nm[q], ax);
            ay = fmaf(vv[q].y, nm[q], ay);
        }
    }
    for (; j + 4 <= k; j += 4) {
        int r0 = rs[s0 + j], r1 = rs[s0 + j + 1], r2 = rs[s0 + j + 2], r3 = rs[s0 + j + 3];
        float n0 = dinv[r0] * dv, n1 = dinv[r1] * dv, n2 = dinv[r2] * dv, n3 = dinv[r3] * dv;
        float2 v0 = __half22float2(hv[(size_t)r0 * 32 + l]);
        float2 v1 = __half22float2(hv[(size_t)r1 * 32 + l]);
        float2 v2 = __half22float2(hv[(size_t)r2 * 32 + l]);
        float2 v3 = __half22float2(hv[(size_t)r3 * 32 + l]);
        ax = fmaf(v0.x, n0, ax); ay = fmaf(v0.y, n0, ay);
        ax = fmaf(v1.x, n1, ax); ay = fmaf(v1.y, n1, ay);
        ax = fmaf(v2.x, n2, ax); ay = fmaf(v2.y, n2, ay);
        ax = fmaf(v3.x, n3, ax); ay = fmaf(v3.y, n3, ay);
    }
    for (; j < k; ++j) {
        int r = rs[s0 + j];
        float nm = dinv[r] * dv;
        float2 vv = __half22float2(hv[(size_t)r * 32 + l]);
        ax = fmaf(vv.x, nm, ax);
        ay = fmaf(vv.y, nm, ay);
    }
    *(float2*)(out + (size_t)n * OUTC + 2 * l) = make_float2(ax, ay);
}

extern "C" void kernel_launch(void* const* d_in, const int* in_sizes, int n_in,
                              void* d_out, int out_size, void* d_ws, size_t ws_size,
                              hipStream_t stream) {
    const float* x  = (const float*)d_in[0];
    const int*   ei = (const int*)d_in[1];
    const float* W1 = (const float*)d_in[2];
    const float* b1 = (const float*)d_in[3];
    const float* W2 = (const float*)d_in[4];
    const float* b2 = (const float*)d_in[5];
    float* out = (float*)d_out;

    const int N = in_sizes[0] / IN_CH;
    const int E = in_sizes[1] / 2;
    const int* row = ei;
    const int* col = ei + E;
    const int NB = (N + 127) >> BSH;  // 782 for N=100000 (<= NBMAX)

    char* ws = (char*)d_ws;
    int*    bcnt   = (int*)ws;                      // NB (zeroed by k_init)
    int*    bstart = bcnt + NBMAX;                  // NB+1
    int*    gcur   = bstart + NBMAX + 8;            // NB
    int*    start  = gcur + NBMAX;                  // N+1
    float*  dinv   = (float*)(start + N + 8);       // N
    char*   p      = (char*)(dinv + N);
    p = (char*)(((uintptr_t)p + 255) & ~(uintptr_t)255);
    int*    bbuf   = (int*)p;                       // E packed ints (6.4 MB)
    int*    rs     = bbuf + E;                      // E ints (6.4 MB)
    __half* x16    = (__half*)(rs + E);             // N*12 fp16
    float*  aggx   = (float*)(x16 + (size_t)N * IN_CH + 8);   // N*12 f32
    __half* h2     = (__half*)(aggx + (size_t)N * IN_CH);     // N*64 fp16

    const int nchunks = (E + CHUNK - 1) / CHUNK;

    k_init<<<(N * IN_CH + 255) / 256, 256, 0, stream>>>(bcnt, NB, x, x16, N * IN_CH);
    k_bhist<<<nchunks, 256, 0, stream>>>(col, bcnt, E, NB);
    k_bscan<<<1, 256, 0, stream>>>(bcnt, bstart, gcur, start + N, E, NB);
    k_bucket<<<nchunks, 256, 0, stream>>>(row, col, gcur, bbuf, E, NB);
    k_csr<<<NB, 256, 0, stream>>>(bstart, bbuf, start, dinv, rs, N);

    k_gather_x<<<(N + 15) / 16, 192, 0, stream>>>(start, dinv, rs, x16, aggx, N);
    k_mlp<<<(N + 63) / 64, 256, 0, stream>>>(aggx, W1, b1, W2, h2, N);
    k_gather2<<<(N + 7) / 8, 256, 0, stream>>>(start, dinv, rs, h2, b2, out, N);
}

// Round 19
// 136.688 us; speedup vs baseline: 1.3316x; 1.1241x over previous
//
#include <hip/hip_runtime.h>
#include <hip/hip_fp16.h>

// 2-layer GCN, CSR-gather formulation (no float atomics).
// A_norm·(x@W1) = (A_norm·x)@W1 -> layer-1 aggregation in 12-ch space.
// CSR by LDS bucket sort into FIXED 4096-slot per-bucket regions (r19):
// no pre-histogram pass; gcur atomics allocate, bscan compacts post-hoc.
// bbuf packed: (row<<7)|local_col (row < 2^17). rs payload = row only.
// RACE LESSON (r11): gather source values (dinv/x) must come from a PRIOR kernel.
// LAYOUT LESSON (r13): channel-slicing h2 trades traffic for 3x instructions.
// NT LESSON (r8/r15): nontemporal hints net-negative here (both directions).
// gather2 (r16/r19): 4 nodes/wave, 4 ch/lane via b64 -> issue count /4.
// MLP (r18): MFMA, hidden computed into A-frags in regs, W2^T LDS b128 frags.
// x and h2 in fp16 (measured safe r8-r18). MLP fused per 64-node tile.

#define IN_CH 12
#define HID 128
#define OUTC 64
#define BSH 7      // bucket = 128 dest nodes
#define NBMAX 1024 // supports N <= 131072
#define CHUNK 4096 // edges per k_bucket block
#define SORTMAX 4096
#define SLOT 4096  // per-bucket region slots (counts ~2048+-45: 40 sigma headroom)
#define W2TS 136   // w2t row stride in halfs (272B: 16B-aligned b128, 2-way banks)

typedef _Float16 f16x8 __attribute__((ext_vector_type(8)));
typedef float f32x4 __attribute__((ext_vector_type(4)));

// fused init: zero gcur + convert x -> fp16
__global__ void k_init(int* __restrict__ gcur, int nb,
                       const float* __restrict__ x, __half* __restrict__ x16, int n) {
    int i = blockIdx.x * blockDim.x + threadIdx.x;
    if (i < nb) gcur[i] = 0;
    if (i < n) x16[i] = __float2half(x[i]);
}

// ---- pass 1: LDS-staged bucket append into fixed per-bucket regions ----
__global__ __launch_bounds__(256) void k_bucket(
    const int* __restrict__ row, const int* __restrict__ col,
    int* __restrict__ gcur, int* __restrict__ bbuf, int E, int NB) {
    __shared__ int lh[NBMAX], lstart[NBMAX], lcur[NBMAX], gb[NBMAX];
    __shared__ int part[256];
    __shared__ int2 lbuf[CHUNK];  // 32 KiB
    int t = threadIdx.x;
    for (int i = t; i < NB; i += 256) lh[i] = 0;
    __syncthreads();
    int base0 = blockIdx.x * CHUNK;
    int end = min(base0 + CHUNK, E);
    for (int e = base0 + t; e < end; e += 256)
        atomicAdd(&lh[col[e] >> BSH], 1);
    __syncthreads();
    int v[4]; int s = 0;
#pragma unroll
    for (int j = 0; j < 4; ++j) { int b = t * 4 + j; v[j] = (b < NB) ? lh[b] : 0; s += v[j]; }
    part[t] = s;
    __syncthreads();
    for (int off = 1; off < 256; off <<= 1) {
        int u = (t >= off) ? part[t - off] : 0;
        __syncthreads();
        part[t] += u;
        __syncthreads();
    }
    int pb = (t > 0) ? part[t - 1] : 0;
#pragma unroll
    for (int j = 0; j < 4; ++j) {
        int b = t * 4 + j;
        if (b < NB) lstart[b] = pb;
        pb += v[j];
    }
    __syncthreads();
    for (int i = t; i < NB; i += 256) {
        int c = lh[i];
        gb[i] = c ? atomicAdd(&gcur[i], c) : 0;  // unseeded: region-local offset
        lcur[i] = lstart[i];
    }
    __syncthreads();
    for (int e = base0 + t; e < end; e += 256) {
        int c = col[e];
        int p = atomicAdd(&lcur[c >> BSH], 1);
        lbuf[p] = make_int2(row[e], c);
    }
    __syncthreads();
    int cN = end - base0;
    for (int i = t; i < cN; i += 256) {
        int2 rc = lbuf[i];
        int b = rc.y >> BSH;
        bbuf[(size_t)b * SLOT + gb[b] + (i - lstart[b])] = (rc.x << BSH) | (rc.y & 127);
    }
}

// ---- pass 2: scan post-hoc bucket counts (gcur) -> bstart; start[N]=E ----
__global__ __launch_bounds__(256) void k_bscan(
    const int* __restrict__ gcur, int* __restrict__ bstart,
    int* __restrict__ startN, int E, int NB) {
    __shared__ int part[256];
    int t = threadIdx.x;
    int v[4]; int s = 0;
#pragma unroll
    for (int j = 0; j < 4; ++j) { int b = t * 4 + j; v[j] = (b < NB) ? gcur[b] : 0; s += v[j]; }
    part[t] = s;
    __syncthreads();
    for (int off = 1; off < 256; off <<= 1) {
        int u = (t >= off) ? part[t - off] : 0;
        __syncthreads();
        part[t] += u;
        __syncthreads();
    }
    int base = (t > 0) ? part[t - 1] : 0;
#pragma unroll
    for (int j = 0; j < 4; ++j) {
        int b = t * 4 + j;
        if (b < NB) bstart[b] = base;
        base += v[j];
    }
    if (t == 255) bstart[NB] = base;  // == E
    if (t == 0) *startN = E;          // start[N] = E
}

// ---- pass 3: per-bucket CSR: start/dinv + LDS sort -> coalesced rs write ----
__global__ __launch_bounds__(256) void k_csr(
    const int* __restrict__ bstart, const int* __restrict__ bbuf,
    int* __restrict__ start, float* __restrict__ dinv,
    int* __restrict__ rs, int N) {
    int me = blockIdx.x;
    int lo = me << BSH;
    int bs = bstart[me];
    int cntb = bstart[me + 1] - bs;
    const int* src = bbuf + (size_t)me * SLOT;
    __shared__ int lh[128], lsc[128];
    __shared__ int lsort[SORTMAX];  // 16 KiB
    int t = threadIdx.x;
    bool lds_ok = (cntb <= SORTMAX);
    if (t < 128) lh[t] = 0;
    __syncthreads();
    for (int i = t; i < cntb; i += 256)
        atomicAdd(&lh[src[i] & 127], 1);
    __syncthreads();
    if (t < 128) lsc[t] = lh[t];
    __syncthreads();
    for (int off = 1; off < 128; off <<= 1) {
        int u = (t < 128 && t >= off) ? lsc[t - off] : 0;
        __syncthreads();
        if (t < 128) lsc[t] += u;
        __syncthreads();
    }
    if (t < 128) {
        int excl = lsc[t] - lh[t];
        int n = lo + t;
        if (n < N) {
            start[n] = bs + excl;
            dinv[n] = rsqrtf((float)lh[t] + 1.0f);
        }
        lsc[t] = excl;  // reuse as cursor
    }
    __syncthreads();
    for (int i = t; i < cntb; i += 256) {
        int v = src[i];
        int p = atomicAdd(&lsc[v & 127], 1);
        int r = v >> BSH;
        if (lds_ok) lsort[p] = r; else rs[bs + p] = r;
    }
    __syncthreads();
    if (lds_ok)  // coalesced rs write-out
        for (int i = t; i < cntb; i += 256) rs[bs + i] = lsort[i];
}

// ---- layer 1 gather: aggx = A_norm·x (12 ch, fp16 x, 8-deep pipeline) ----
__global__ __launch_bounds__(192) void k_gather_x(
    const int* __restrict__ start, const float* __restrict__ dinv,
    const int* __restrict__ rs, const __half* __restrict__ x16,
    float* __restrict__ aggx, int N) {
    int ln = threadIdx.x / 12;
    int c  = threadIdx.x % 12;
    int n  = blockIdx.x * 16 + ln;
    if (n >= N) return;
    float dv = dinv[n];
    int s0 = start[n], k = start[n + 1] - s0;
    float acc = __half2float(x16[(size_t)n * IN_CH + c]) * dv * dv;
    int j = 0;
    for (; j + 8 <= k; j += 8) {
        int r[8];
#pragma unroll
        for (int q = 0; q < 8; ++q) r[q] = rs[s0 + j + q];
        float nm[8], vv[8];
#pragma unroll
        for (int q = 0; q < 8; ++q) nm[q] = dinv[r[q]] * dv;
#pragma unroll
        for (int q = 0; q < 8; ++q) vv[q] = __half2float(x16[(size_t)r[q] * IN_CH + c]);
#pragma unroll
        for (int q = 0; q < 8; ++q) acc = fmaf(vv[q], nm[q], acc);
    }
    for (; j + 4 <= k; j += 4) {
        int r0 = rs[s0 + j], r1 = rs[s0 + j + 1], r2 = rs[s0 + j + 2], r3 = rs[s0 + j + 3];
        float n0 = dinv[r0] * dv, n1 = dinv[r1] * dv, n2 = dinv[r2] * dv, n3 = dinv[r3] * dv;
        float v0 = __half2float(x16[(size_t)r0 * IN_CH + c]);
        float v1 = __half2float(x16[(size_t)r1 * IN_CH + c]);
        float v2 = __half2float(x16[(size_t)r2 * IN_CH + c]);
        float v3 = __half2float(x16[(size_t)r3 * IN_CH + c]);
        acc = fmaf(v0, n0, acc); acc = fmaf(v1, n1, acc);
        acc = fmaf(v2, n2, acc); acc = fmaf(v3, n3, acc);
    }
    for (; j < k; ++j) {
        int r = rs[s0 + j];
        acc = fmaf(__half2float(x16[(size_t)r * IN_CH + c]), dinv[r] * dv, acc);
    }
    aggx[(size_t)n * IN_CH + c] = acc;
}

// ---- fused MLP via MFMA: h2 = fp16( relu(aggx@W1 + b1) @ W2 ) ----
__global__ __launch_bounds__(256) void k_mlp(
    const float* __restrict__ aggx, const float* __restrict__ W1,
    const float* __restrict__ b1, const float* __restrict__ W2,
    __half* __restrict__ h2, int N) {
    __shared__ _Float16 w2t[OUTC * W2TS];   // W2^T [c][k], 17 KiB
    __shared__ _Float16 w1h[IN_CH * HID];   // W1 [j][k], 3 KiB
    int t = threadIdx.x;
    for (int i = t; i < HID * OUTC; i += 256) {
        int k = i >> 6, c = i & 63;
        w2t[c * W2TS + k] = (_Float16)W2[i];
    }
    for (int i = t; i < IN_CH * HID; i += 256)
        w1h[i] = (_Float16)W1[i];
    __syncthreads();

    int lane = t & 63;
    int wv   = t >> 6;               // wave 0..3
    int mrow = lane & 15;            // A-row / B-col / D-col within tile
    int kg   = lane >> 4;            // k-group 0..3
    long long base = (long long)blockIdx.x * 64 + wv * 16;
    long long nrow = base + mrow;
    long long ncl  = (nrow < N) ? nrow : (long long)(N - 1);

    float ax[12];
    {
        const float4* ap = (const float4*)(aggx + ncl * IN_CH);
        float4 a0 = ap[0], a1 = ap[1], a2 = ap[2];
        ax[0] = a0.x; ax[1] = a0.y; ax[2]  = a0.z; ax[3]  = a0.w;
        ax[4] = a1.x; ax[5] = a1.y; ax[6]  = a1.z; ax[7]  = a1.w;
        ax[8] = a2.x; ax[9] = a2.y; ax[10] = a2.z; ax[11] = a2.w;
    }

    f32x4 acc[4] = {{0.f,0.f,0.f,0.f}, {0.f,0.f,0.f,0.f},
                    {0.f,0.f,0.f,0.f}, {0.f,0.f,0.f,0.f}};
#pragma unroll
    for (int f = 0; f < 4; ++f) {
        int kk = f * 32 + kg * 8;
        float hv[8];
        float4 bb0 = *(const float4*)(b1 + kk);
        float4 bb1 = *(const float4*)(b1 + kk + 4);
        hv[0] = bb0.x; hv[1] = bb0.y; hv[2] = bb0.z; hv[3] = bb0.w;
        hv[4] = bb1.x; hv[5] = bb1.y; hv[6] = bb1.z; hv[7] = bb1.w;
#pragma unroll
        for (int j = 0; j < IN_CH; ++j) {
            const __half2* wp = (const __half2*)(w1h + j * HID + kk);  // broadcast
            float2 w0 = __half22float2(wp[0]);
            float2 w1v = __half22float2(wp[1]);
            float2 w2v = __half22float2(wp[2]);
            float2 w3 = __half22float2(wp[3]);
            float a = ax[j];
            hv[0] = fmaf(a, w0.x, hv[0]);  hv[1] = fmaf(a, w0.y, hv[1]);
            hv[2] = fmaf(a, w1v.x, hv[2]); hv[3] = fmaf(a, w1v.y, hv[3]);
            hv[4] = fmaf(a, w2v.x, hv[4]); hv[5] = fmaf(a, w2v.y, hv[5]);
            hv[6] = fmaf(a, w3.x, hv[6]);  hv[7] = fmaf(a, w3.y, hv[7]);
        }
        f16x8 af;
#pragma unroll
        for (int i = 0; i < 8; ++i) af[i] = (_Float16)fmaxf(hv[i], 0.0f);
#pragma unroll
        for (int c = 0; c < 4; ++c) {
            f16x8 bf = *(const f16x8*)(w2t + (c * 16 + mrow) * W2TS + kk);
            acc[c] = __builtin_amdgcn_mfma_f32_16x16x32_f16(af, bf, acc[c], 0, 0, 0);
        }
    }
#pragma unroll
    for (int r = 0; r < 4; ++r) {
        long long node = base + kg * 4 + r;
        if (node < N) {
            __half* dp = h2 + node * OUTC + mrow;
#pragma unroll
            for (int c = 0; c < 4; ++c)
                dp[c * 16] = __float2half(acc[c][r]);
        }
    }
}

// ---- layer 2 gather: out = A_norm·h2 + b2 ----
// 4 nodes per wave (quarter-wave each), 4 channels per lane via one b64 load.
__global__ __launch_bounds__(256) void k_gather2(
    const int* __restrict__ start, const float* __restrict__ dinv,
    const int* __restrict__ rs, const __half* __restrict__ h2,
    const float* __restrict__ b2, float* __restrict__ out, int N) {
    int n = blockIdx.x * 16 + (threadIdx.x >> 4);  // 16 nodes per 256-thr block
    if (n >= N) return;
    int l = threadIdx.x & 15;                      // channels 4l..4l+3
    float dv = dinv[n];
    int s0 = start[n], k = start[n + 1] - s0;
    float4 bb = *(const float4*)(b2 + 4 * l);
    uint2 hu = *(const uint2*)(h2 + (size_t)n * OUTC + 4 * l);
    float2 h0 = __half22float2(*(__half2*)&hu.x);
    float2 h1 = __half22float2(*(__half2*)&hu.y);
    float dvv = dv * dv;
    float a0 = fmaf(h0.x, dvv, bb.x);
    float a1 = fmaf(h0.y, dvv, bb.y);
    float a2 = fmaf(h1.x, dvv, bb.z);
    float a3 = fmaf(h1.y, dvv, bb.w);
    int j = 0;
    for (; j + 8 <= k; j += 8) {
        int r[8];
#pragma unroll
        for (int q = 0; q < 8; ++q) r[q] = rs[s0 + j + q];
        float nm[8];
#pragma unroll
        for (int q = 0; q < 8; ++q) nm[q] = dinv[r[q]] * dv;
        uint2 vv[8];
#pragma unroll
        for (int q = 0; q < 8; ++q) vv[q] = *(const uint2*)(h2 + (size_t)r[q] * OUTC + 4 * l);
#pragma unroll
        for (int q = 0; q < 8; ++q) {
            float2 lo = __half22float2(*(__half2*)&vv[q].x);
            float2 hi = __half22float2(*(__half2*)&vv[q].y);
            a0 = fmaf(lo.x, nm[q], a0);
            a1 = fmaf(lo.y, nm[q], a1);
            a2 = fmaf(hi.x, nm[q], a2);
            a3 = fmaf(hi.y, nm[q], a3);
        }
    }
    for (; j + 4 <= k; j += 4) {
        int r[4];
#pragma unroll
        for (int q = 0; q < 4; ++q) r[q] = rs[s0 + j + q];
        float nm[4];
#pragma unroll
        for (int q = 0; q < 4; ++q) nm[q] = dinv[r[q]] * dv;
        uint2 vv[4];
#pragma unroll
        for (int q = 0; q < 4; ++q) vv[q] = *(const uint2*)(h2 + (size_t)r[q] * OUTC + 4 * l);
#pragma unroll
        for (int q = 0; q < 4; ++q) {
            float2 lo = __half22float2(*(__half2*)&vv[q].x);
            float2 hi = __half22float2(*(__half2*)&vv[q].y);
            a0 = fmaf(lo.x, nm[q], a0);
            a1 = fmaf(lo.y, nm[q], a1);
            a2 = fmaf(hi.x, nm[q], a2);
            a3 = fmaf(hi.y, nm[q], a3);
        }
    }
    for (; j < k; ++j) {
        int r = rs[s0 + j];
        float nm = dinv[r] * dv;
        uint2 vv = *(const uint2*)(h2 + (size_t)r * OUTC + 4 * l);
        float2 lo = __half22float2(*(__half2*)&vv.x);
        float2 hi = __half22float2(*(__half2*)&vv.y);
        a0 = fmaf(lo.x, nm, a0);
        a1 = fmaf(lo.y, nm, a1);
        a2 = fmaf(hi.x, nm, a2);
        a3 = fmaf(hi.y, nm, a3);
    }
    *(float4*)(out + (size_t)n * OUTC + 4 * l) = make_float4(a0, a1, a2, a3);
}

extern "C" void kernel_launch(void* const* d_in, const int* in_sizes, int n_in,
                              void* d_out, int out_size, void* d_ws, size_t ws_size,
                              hipStream_t stream) {
    const float* x  = (const float*)d_in[0];
    const int*   ei = (const int*)d_in[1];
    const float* W1 = (const float*)d_in[2];
    const float* b1 = (const float*)d_in[3];
    const float* W2 = (const float*)d_in[4];
    const float* b2 = (const float*)d_in[5];
    float* out = (float*)d_out;

    const int N = in_sizes[0] / IN_CH;
    const int E = in_sizes[1] / 2;
    const int* row = ei;
    const int* col = ei + E;
    const int NB = (N + 127) >> BSH;  // 782 for N=100000 (<= NBMAX)

    char* ws = (char*)d_ws;
    int*    gcur   = (int*)ws;                      // NB (zeroed by k_init)
    int*    bstart = gcur + NBMAX;                  // NB+1
    int*    start  = bstart + NBMAX + 8;            // N+1
    float*  dinv   = (float*)(start + N + 8);       // N
    char*   p      = (char*)(dinv + N);
    p = (char*)(((uintptr_t)p + 255) & ~(uintptr_t)255);
    int*    bbuf   = (int*)p;                       // NB*SLOT ints (12.8 MB)
    int*    rs     = bbuf + (size_t)NBMAX * SLOT;   // E ints (6.4 MB)
    __half* x16    = (__half*)(rs + E);             // N*12 fp16
    float*  aggx   = (float*)(x16 + (size_t)N * IN_CH + 8);   // N*12 f32
    __half* h2     = (__half*)(aggx + (size_t)N * IN_CH);     // N*64 fp16

    const int nchunks = (E + CHUNK - 1) / CHUNK;

    k_init<<<(N * IN_CH + 255) / 256, 256, 0, stream>>>(gcur, NB, x, x16, N * IN_CH);
    k_bucket<<<nchunks, 256, 0, stream>>>(row, col, gcur, bbuf, E, NB);
    k_bscan<<<1, 256, 0, stream>>>(gcur, bstart, start + N, E, NB);
    k_csr<<<NB, 256, 0, stream>>>(bstart, bbuf, start, dinv, rs, N);

    k_gather_x<<<(N + 15) / 16, 192, 0, stream>>>(start, dinv, rs, x16, aggx, N);
    k_mlp<<<(N + 63) / 64, 256, 0, stream>>>(aggx, W1, b1, W2, h2, N);
    k_gather2<<<(N + 15) / 16, 256, 0, stream>>>(start, dinv, rs, h2, b2, out, N);
}